// Round 1
// baseline (1587.712 us; speedup 1.0000x reference)
//
#include <hip/hip_runtime.h>

// Problem constants
#define NVOLS 24
#define NPTS  32768
#define NIND  18
#define NFEAT 42
#define RES   16
#define HID   32
#define DIN   126   // NFEAT*3
#define NOUTC 144

#define TPB   256
#define PPB   256                     // points per block (1 pt/thread)
#define BLOCKS_PER_VOL (NPTS / PPB)   // 128

// LDS: features + per-wave 64x32 XOR-swizzled transpose buffer
#define SFEAT_N (3 * NFEAT * RES)     // 2016 floats = 8064 B
#define SW_COLS 32
#define SW_ROWS 64
#define SW_N    (SW_ROWS * SW_COLS)   // 2048 floats = 8192 B per wave
// total = 8064 + 4*8192 = 40,832 B -> 4 blocks/CU (163,328 <= 160 KiB)

__device__ __forceinline__ void lds_fence() {
    __asm__ volatile("s_waitcnt lgkmcnt(0)" ::: "memory");
}

// ---- layer-2 k-quarter: compute acc = h @ w2[:, K0:K0+KLEN] + b2 ----
// w2/b2 addresses are block-uniform -> scalar loads; h is in VGPRs.
template<int K0, int KLEN>
__device__ __forceinline__ void l2_compute(const float* __restrict__ w2j,
                                           const float* __restrict__ b2j,
                                           const float* __restrict__ h,
                                           float* __restrict__ acc)
{
    #pragma unroll
    for (int kk = 0; kk < KLEN; kk++) acc[kk] = b2j[K0 + kk];
    #pragma unroll
    for (int o = 0; o < HID; o++) {
        float ho = h[o];
        #pragma unroll
        for (int kk = 0; kk < KLEN; kk++)
            acc[kk] = fmaf(ho, w2j[o * DIN + K0 + kk], acc[kk]);  // SGPR operand
    }
}

// deposit acc into the wave-private swizzle buffer: row=lane, col kk -> kk^(lane&31)
// bank for fixed kk = kk^(lane&31): all 32 banks, 2 lanes/bank -> conflict-free.
template<int KLEN>
__device__ __forceinline__ void l2_stage(float* __restrict__ swr, int lane,
                                         const float* __restrict__ acc)
{
    lds_fence();                         // prior drain's reads fully retired
    const int s = lane & 31;
    float* row = swr + lane * SW_COLS;
    #pragma unroll
    for (int kk = 0; kk < KLEN; kk++)
        row[kk ^ s] = acc[kk];
}

// transposed read-back + coalesced float2 stores of cols [K0, K0+KLEN)
// pair {2m^s, 2m+1^s} lives at the aligned b64 slot (2m)^(s&30); swap if s odd.
template<int K0, int KLEN>
__device__ __forceinline__ void l2_drain(const float* __restrict__ swr, int lane,
                                         float* __restrict__ outw)
{
    lds_fence();                         // stage's writes visible wave-wide
    constexpr int PAIRS = KLEN / 2;      // 16 or 15
    #pragma unroll
    for (int i = 0; i < PAIRS; i++) {
        int u  = i * 64 + lane;          // PAIRS*64 units = 64 pts x PAIRS pairs
        int pr = u / PAIRS;
        int m  = u - pr * PAIRS;
        int sp = pr & 31;
        const float* slot = swr + pr * SW_COLS + ((2 * m) ^ (sp & 30));
        float2 t = *(const float2*)slot;
        float a0 = (sp & 1) ? t.y : t.x;
        float a1 = (sp & 1) ? t.x : t.y;
        *(float2*)(outw + pr * NOUTC + NIND + K0 + 2 * m) = make_float2(a0, a1);
    }
}

__global__ __launch_bounds__(TPB, 4) void fused_gridsample_mlp(
    const float* __restrict__ pts,      // (J, P, 3)
    const float* __restrict__ feature,  // (J, F, R, 3)
    const float* __restrict__ ind,      // (J, P, 18)
    const float* __restrict__ w1,       // (J, 126, 32)
    const float* __restrict__ b1,       // (J, 32)
    const float* __restrict__ w2,       // (J, 32, 126)
    const float* __restrict__ b2,       // (J, 126)
    float* __restrict__ out)            // (J, P, 144)
{
    __shared__ float sfeat[SFEAT_N];
    __shared__ float swout[4][SW_N];

    const int tid   = threadIdx.x;
    const int j     = blockIdx.x / BLOCKS_PER_VOL;
    const int pbase = (blockIdx.x % BLOCKS_PER_VOL) * PPB;
    const int wave  = tid >> 6;
    const int lane  = tid & 63;

    // ---- stage feature[j] -> LDS as [c][f][r] ----
    const float* fj = feature + j * (NFEAT * RES * 3);
    for (int e = tid; e < SFEAT_N; e += TPB) {
        int f   = e / (RES * 3);
        int rem = e - f * (RES * 3);
        int r   = rem / 3;
        int c   = rem - r * 3;
        sfeat[(c * NFEAT + f) * RES + r] = fj[e];
    }

    // ---- interp setup (1 point per thread); reads only pts ----
    const int p = pbase + tid;
    float wfr[3]; int xb[3];
    {
        const float* pp = pts + (size_t)(j * NPTS + p) * 3;
        #pragma unroll
        for (int c = 0; c < 3; c++) {
            float x = (pp[c] + 1.0f) * 7.5f;
            x = fminf(fmaxf(x, 0.0f), 15.0f);
            int x0 = (int)x;            // x >= 0 -> trunc == floor
            x0 = min(x0, RES - 2);
            wfr[c] = x - (float)x0;
            xb[c]  = c * (NFEAT * RES) + x0;
        }
    }

    // ---- ind passthrough: wave-private, no barrier needed, overlaps staging ----
    {
        const int wbase = pbase + wave * 64;
        const float* indw = ind + (size_t)(j * NPTS + wbase) * NIND;
        float* outw       = out + (size_t)(j * NPTS + wbase) * NOUTC;
        #pragma unroll
        for (int i = 0; i < 9; i++) {        // 64 pts * 9 f2 = 576 units / 64 lanes
            int u = i * 64 + lane;
            float2 v = ((const float2*)indw)[u];
            int pr = u / 9;
            int m  = u - pr * 9;
            *(float2*)(outw + pr * NOUTC + 2 * m) = v;
        }
    }

    __syncthreads();   // sfeat ready — the ONLY block-wide barrier

    // ---- layer 1: h = relu(v @ w1 + b1), weights via scalar loads ----
    const float* w1j = w1 + j * (DIN * HID);
    const float* b1j = b1 + j * HID;
    float h[HID];
    #pragma unroll
    for (int o = 0; o < HID; o++) h[o] = b1j[o];

    for (int f = 0; f < NFEAT; f++) {
        #pragma unroll
        for (int c = 0; c < 3; c++) {
            int   idx = xb[c] + f * RES;
            float g0  = sfeat[idx];
            float g1  = sfeat[idx + 1];
            float v   = fmaf(wfr[c], g1 - g0, g0);
            const float* wrow = w1j + (f * 3 + c) * HID;  // block-uniform row
            #pragma unroll
            for (int o = 0; o < HID; o++)
                h[o] = fmaf(v, wrow[o], h[o]);
        }
    }
    #pragma unroll
    for (int o = 0; o < HID; o++) h[o] = fmaxf(h[o], 0.0f);

    // ---- layer 2: wave-private, software-pipelined k-quarters ----
    // drain of quarter n overlaps compute of quarter n+1 (VALU vs LDS/VMEM pipes)
    const float* w2j  = w2 + j * (HID * DIN);
    const float* b2j  = b2 + j * DIN;
    float* const swr  = swout[wave];
    float* const outw = out + (size_t)(j * NPTS + pbase + wave * 64) * NOUTC;

    float accA[32], accB[32];
    l2_compute< 0, 32>(w2j, b2j, h, accA);
    l2_stage<32>(swr, lane, accA);
    l2_compute<32, 32>(w2j, b2j, h, accB);
    l2_drain< 0, 32>(swr, lane, outw);
    l2_stage<32>(swr, lane, accB);
    l2_compute<64, 32>(w2j, b2j, h, accA);
    l2_drain<32, 32>(swr, lane, outw);
    l2_stage<32>(swr, lane, accA);
    l2_compute<96, 30>(w2j, b2j, h, accB);
    l2_drain<64, 32>(swr, lane, outw);
    l2_stage<30>(swr, lane, accB);
    l2_drain<96, 30>(swr, lane, outw);
}

extern "C" void kernel_launch(void* const* d_in, const int* in_sizes, int n_in,
                              void* d_out, int out_size, void* d_ws, size_t ws_size,
                              hipStream_t stream) {
    const float* pts     = (const float*)d_in[0];
    const float* feature = (const float*)d_in[1];
    const float* ind     = (const float*)d_in[2];
    const float* w1      = (const float*)d_in[3];
    const float* b1      = (const float*)d_in[4];
    const float* w2      = (const float*)d_in[5];
    const float* b2      = (const float*)d_in[6];
    float* out           = (float*)d_out;

    dim3 grid(NVOLS * BLOCKS_PER_VOL);   // 24 * 128 = 3072 blocks
    dim3 block(TPB);
    fused_gridsample_mlp<<<grid, block, 0, stream>>>(pts, feature, ind, w1, b1, w2, b2, out);
}

// Round 3
// 1296.598 us; speedup vs baseline: 1.2245x; 1.2245x over previous
//
#include <hip/hip_runtime.h>

// Problem constants
#define NVOLS 24
#define NPTS  32768
#define NIND  18
#define NFEAT 42
#define RES   16
#define HID   32
#define DIN   126   // NFEAT*3
#define NOUTC 144

#define TPB   256
#define PPB   256                     // points per block (1 pt/thread)
#define BLOCKS_PER_VOL (NPTS / PPB)   // 128

// LDS: features + per-wave 64x32 XOR-swizzled transpose buffer
#define SFEAT_N (3 * NFEAT * RES)     // 2016 floats = 8064 B
#define SW_COLS 32
#define SW_N    (64 * SW_COLS)        // 2048 floats = 8192 B per wave
// total = 8064 + 4*8192 = 40,832 B -> 4 blocks/CU

__device__ __forceinline__ void lds_fence() {
    __asm__ volatile("s_waitcnt lgkmcnt(0)" ::: "memory");
}

// ---- layer-2 k-slice: acc[kk] = b2[K0+kk] + sum_o h[o]*w2[o][K0+kk] ----
// w2/b2 addresses are block-uniform -> scalar (SGPR) loads; h in VGPRs.
template<int K0, int KLEN>
__device__ __forceinline__ void l2_compute(const float* __restrict__ w2j,
                                           const float* __restrict__ b2j,
                                           const float* __restrict__ h,
                                           float* __restrict__ acc)
{
    #pragma unroll
    for (int kk = 0; kk < KLEN; kk++) acc[kk] = b2j[K0 + kk];
    #pragma unroll
    for (int o = 0; o < HID; o++) {
        float ho = h[o];
        #pragma unroll
        for (int kk = 0; kk < KLEN; kk++)
            acc[kk] = fmaf(ho, w2j[o * DIN + K0 + kk], acc[kk]);
    }
}

// deposit 32 cols into the wave-private swizzle buffer: row=lane, col kk -> kk^(lane&31)
template<int KLEN>
__device__ __forceinline__ void l2_stage(float* __restrict__ swr, int lane,
                                         const float* __restrict__ acc)
{
    lds_fence();                         // prior drain's reads fully retired
    const int s = lane & 31;
    float* row = swr + lane * SW_COLS;
    #pragma unroll
    for (int kk = 0; kk < KLEN; kk++)
        row[kk ^ s] = acc[kk];
}

// transposed read-back + coalesced float2 stores of mlp cols [K0, K0+KLEN)
template<int K0, int KLEN>
__device__ __forceinline__ void l2_drain(const float* __restrict__ swr, int lane,
                                         float* __restrict__ outw)
{
    lds_fence();                         // stage's writes visible wave-wide
    constexpr int PAIRS = KLEN / 2;      // 16 or 15
    #pragma unroll
    for (int i = 0; i < PAIRS; i++) {
        int u  = i * 64 + lane;          // 64 rows x PAIRS pairs
        int pr = u / PAIRS;
        int m  = u - pr * PAIRS;
        int sp = pr & 31;
        const float* slot = swr + pr * SW_COLS + ((2 * m) ^ (sp & 30));
        float2 t = *(const float2*)slot;
        float a0 = (sp & 1) ? t.y : t.x;
        float a1 = (sp & 1) ? t.x : t.y;
        *(float2*)(outw + pr * NOUTC + NIND + K0 + 2 * m) = make_float2(a0, a1);
    }
}

// first drain: mlp cols [0,32) MERGED with the 18 ind passthrough cols, so each
// row's leading sectors are written in the same pass as the mlp data.
// 25 f2 units per row: m<9 -> ind (global->global), m>=9 -> lds pair (m-9).
__device__ __forceinline__ void l2_drain_a1(const float* __restrict__ swr, int lane,
                                            const float* __restrict__ indw,
                                            float* __restrict__ outw)
{
    lds_fence();
    #pragma unroll
    for (int i = 0; i < 25; i++) {
        int u  = i * 64 + lane;          // 64 rows * 25 units = 1600 exactly
        int pr = u / 25;
        int m  = u - pr * 25;
        if (m < 9) {
            float2 v = ((const float2*)(indw + pr * NIND))[m];
            *(float2*)(outw + pr * NOUTC + 2 * m) = v;
        } else {
            int mm = m - 9;
            int sp = pr & 31;
            const float* slot = swr + pr * SW_COLS + ((2 * mm) ^ (sp & 30));
            float2 t = *(const float2*)slot;
            float a0 = (sp & 1) ? t.y : t.x;
            float a1 = (sp & 1) ? t.x : t.y;
            *(float2*)(outw + pr * NOUTC + NIND + 2 * mm) = make_float2(a0, a1);
        }
    }
}

__global__ __launch_bounds__(TPB)
__attribute__((amdgpu_waves_per_eu(4, 4)))   // LDS caps us at 4 waves/EU anyway;
                                             // pin it so the allocator uses the
                                             // full 128-VGPR budget (no spills)
void fused_gridsample_mlp(
    const float* __restrict__ pts,      // (J, P, 3)
    const float* __restrict__ feature,  // (J, F, R, 3)
    const float* __restrict__ ind,      // (J, P, 18)
    const float* __restrict__ w1,       // (J, 126, 32)
    const float* __restrict__ b1,       // (J, 32)
    const float* __restrict__ w2,       // (J, 32, 126)
    const float* __restrict__ b2,       // (J, 126)
    float* __restrict__ out)            // (J, P, 144)
{
    __shared__ float sfeat[SFEAT_N];
    __shared__ float swout[4][SW_N];

    const int tid   = threadIdx.x;
    const int j     = blockIdx.x / BLOCKS_PER_VOL;
    const int pbase = (blockIdx.x % BLOCKS_PER_VOL) * PPB;
    const int wave  = tid >> 6;
    const int lane  = tid & 63;

    // ---- stage feature[j] -> LDS as [c][f][r] ----
    const float* fj = feature + j * (NFEAT * RES * 3);
    for (int e = tid; e < SFEAT_N; e += TPB) {
        int f   = e / (RES * 3);
        int rem = e - f * (RES * 3);
        int r   = rem / 3;
        int c   = rem - r * 3;
        sfeat[(c * NFEAT + f) * RES + r] = fj[e];
    }

    // ---- interp setup (1 point per thread) ----
    const int p = pbase + tid;
    float wfr[3]; int xb[3];
    {
        const float* pp = pts + (size_t)(j * NPTS + p) * 3;
        #pragma unroll
        for (int c = 0; c < 3; c++) {
            float x = (pp[c] + 1.0f) * 7.5f;
            x = fminf(fmaxf(x, 0.0f), 15.0f);
            int x0 = (int)x;            // x >= 0 -> trunc == floor
            x0 = min(x0, RES - 2);
            wfr[c] = x - (float)x0;
            xb[c]  = c * (NFEAT * RES) + x0;
        }
    }

    __syncthreads();   // sfeat ready — the only block-wide barrier

    // ---- layer 1: h = relu(v @ w1 + b1), weights via scalar loads ----
    const float* w1j = w1 + j * (DIN * HID);
    const float* b1j = b1 + j * HID;
    float h[HID];
    #pragma unroll
    for (int o = 0; o < HID; o++) h[o] = b1j[o];

    for (int f = 0; f < NFEAT; f++) {
        #pragma unroll
        for (int c = 0; c < 3; c++) {
            int   idx = xb[c] + f * RES;
            float g0  = sfeat[idx];
            float g1  = sfeat[idx + 1];
            float v   = fmaf(wfr[c], g1 - g0, g0);
            const float* wrow = w1j + (f * 3 + c) * HID;  // block-uniform row
            #pragma unroll
            for (int o = 0; o < HID; o++)
                h[o] = fmaf(v, wrow[o], h[o]);
        }
    }
    #pragma unroll
    for (int o = 0; o < HID; o++) h[o] = fmaxf(h[o], 0.0f);

    // ---- layer 2: two k-halves; each half staged+drained in two adjacent
    // 32-col sub-passes. Row visits: {ind+cols 18..82} then {cols 82..143} —
    // adjacent in time, so output lines are written out once. ----
    const float* w2j  = w2 + j * (HID * DIN);
    const float* b2j  = b2 + j * DIN;
    float* const swr  = swout[wave];
    const int    wbase = pbase + wave * 64;
    const float* indw = ind + (size_t)(j * NPTS + wbase) * NIND;
    float* const outw = out + (size_t)(j * NPTS + wbase) * NOUTC;

    float acc[64];
    l2_compute<0, 64>(w2j, b2j, h, acc);       // h[32]+acc[64] live: ~105 VGPR
    l2_stage<32>(swr, lane, acc);
    l2_drain_a1(swr, lane, indw, outw);        // ind cols 0..17 + mlp 18..49
    l2_stage<32>(swr, lane, acc + 32);
    l2_drain<32, 32>(swr, lane, outw);         // cols 50..81

    l2_compute<64, 62>(w2j, b2j, h, acc);
    l2_stage<32>(swr, lane, acc);
    l2_drain<64, 32>(swr, lane, outw);         // cols 82..113
    l2_stage<30>(swr, lane, acc + 32);
    l2_drain<96, 30>(swr, lane, outw);         // cols 114..143
}

extern "C" void kernel_launch(void* const* d_in, const int* in_sizes, int n_in,
                              void* d_out, int out_size, void* d_ws, size_t ws_size,
                              hipStream_t stream) {
    const float* pts     = (const float*)d_in[0];
    const float* feature = (const float*)d_in[1];
    const float* ind     = (const float*)d_in[2];
    const float* w1      = (const float*)d_in[3];
    const float* b1      = (const float*)d_in[4];
    const float* w2      = (const float*)d_in[5];
    const float* b2      = (const float*)d_in[6];
    float* out           = (float*)d_out;

    dim3 grid(NVOLS * BLOCKS_PER_VOL);   // 24 * 128 = 3072 blocks
    dim3 block(TPB);
    fused_gridsample_mlp<<<grid, block, 0, stream>>>(pts, feature, ind, w1, b1, w2, b2, out);
}